// Round 5
// baseline (325.826 us; speedup 1.0000x reference)
//
#include <hip/hip_runtime.h>

typedef float f32x4 __attribute__((ext_vector_type(4)));
typedef short s16x8 __attribute__((ext_vector_type(8)));
typedef unsigned int u32x4 __attribute__((ext_vector_type(4)));
typedef unsigned short u16;
typedef unsigned int u32;

#define QK_SCALE 0.17677669529663687f  // 32^-0.5

__device__ __forceinline__ u16 f2bf(float f) {
    unsigned u = __builtin_bit_cast(unsigned, f);
    u = (u + 0x7fffu + ((u >> 16) & 1u)) >> 16;
    return (u16)u;
}

// packed f32->bf16 pair (RTNE bit-trick; same rounding as f2bf everywhere)
__device__ __forceinline__ u32 pk2(float lo, float hi) {
    return (u32)f2bf(lo) | ((u32)f2bf(hi) << 16);
}

// ---- workspace byte offsets ----
// qkvwC : 196608 bf16 = 393216 B   [h8][t6][ks8][lane64][e8]
// projwC:  65536 bf16 = 131072 B   [nt16][ks8][lane64][e8]
// biasC :  32768 f32  = 131072 B   [h8][tile16][lane64][j4]  (k>=49 -> -1e30 folded in)
// maskC : 262144 f32  = 1048576 B  [wi64][tile16][lane64][j4]
#define WS_PROJW 393216
#define WS_BIASC 524288
#define WS_MASKC 655360

__global__ void prep(const float* __restrict__ qkv_w, const float* __restrict__ proj_w,
                     const float* __restrict__ bias_table, const int* __restrict__ rel_index,
                     const float* __restrict__ mask,
                     u16* __restrict__ qkvwC, u16* __restrict__ projwC,
                     float* __restrict__ biasC, float* __restrict__ maskC) {
    int i = blockIdx.x * 256 + threadIdx.x;
    if (i < 196608) {                       // qkv weights -> fragment order
        int e = i & 7, lane = (i >> 3) & 63, ks = (i >> 9) & 7, i2 = i >> 12;
        int t = i2 % 6, h = i2 / 6;
        int c = lane & 15, g = lane >> 4;
        int wrow = (t >> 1) * 256 + h * 32 + (t & 1) * 16 + c;
        qkvwC[i] = f2bf(qkv_w[wrow * 256 + ks * 32 + g * 8 + e]);
    }
    if (i < 65536) {                        // proj weights -> fragment order
        int e = i & 7, lane = (i >> 3) & 63, ks = (i >> 9) & 7, nt = (i >> 12) & 15;
        int c = lane & 15, g = lane >> 4;
        projwC[i] = f2bf(proj_w[(nt * 16 + c) * 256 + ks * 32 + g * 8 + e]);
    }
    if (i < 32768) {                        // rel-pos bias -> C-fragment order
        int j = i & 3, lane = (i >> 2) & 63, tile = (i >> 8) & 15, h = i >> 12;
        int mt = tile >> 2, nt = tile & 3, g = lane >> 4, c = lane & 15;
        int q = mt * 16 + g * 4 + j, k = nt * 16 + c;
        float v;
        if (k < 49) v = (q < 49) ? bias_table[rel_index[q * 49 + k] * 8 + h] : 0.f;
        else        v = -1e30f;             // pad-column mask folded in
        biasC[i] = v;
    }
    if (i < 262144) {                       // shift mask -> C-fragment order
        int j = i & 3, lane = (i >> 2) & 63, tile = (i >> 8) & 15, wi = i >> 12;
        int mt = tile >> 2, nt = tile & 3, g = lane >> 4, c = lane & 15;
        int q = mt * 16 + g * 4 + j, k = nt * 16 + c;
        maskC[i] = (q < 49 && k < 49) ? mask[wi * 2401 + q * 49 + k] : 0.f;
    }
}

// ---- LDS layout (ushort offsets), total 25216 ushorts = 50,432 B -> 3 blocks/CU ----
// wave scratch at PW = wv*6304:
//   Q  : PW,        stride 40, rows<50 (2000)
//   K  : PW+2000,   stride 40, rows<50 (2000)
//   VT : PW+4000,   stride 72, 32 d-rows x 64 m (2304)
//   P  : PW (overlaps dead Q+K), stride 72, rows<50 (3600 <= 4000)
// OUTS : base 0 (overlaps wave scratch after barrier), stride 264, 49 rows (12936)
__global__ __launch_bounds__(256, 3)
void swin_attn(const float* __restrict__ x,
               const float* __restrict__ qkv_b,
               const float* __restrict__ proj_b,
               const u16* __restrict__ qkvwC,
               const u16* __restrict__ projwC,
               const float* __restrict__ biasC,
               const float* __restrict__ maskC,
               float* __restrict__ out) {
    __shared__ __align__(16) u16 sm[25216];
    const int b = blockIdx.x, tid = threadIdx.x;
    const int wv = tid >> 6, lane = tid & 63, g = lane >> 4, c = lane & 15;
    const int wi = b & 63;
    const int PW = wv * 6304;
    const float* xw = x + (size_t)b * 12544;

    // per-mt clamped x row base (rows >=49 read row 48 but get zeroed below)
    const float* xbase[4];
#pragma unroll
    for (int mt = 0; mt < 4; ++mt) {
        int row = mt * 16 + c; row = row > 48 ? 48 : row;
        xbase[mt] = xw + row * 256;
    }
    const s16x8 zfrag = {0, 0, 0, 0, 0, 0, 0, 0};

    u32 opk[2][4][2][2];   // packed bf16 head outputs

#pragma unroll
    for (int hl = 0; hl < 2; ++hl) {
        const int hh = wv * 2 + hl;

        // ---- QKV projection in two 3-tile halves (keeps VGPR pressure low) ----
#pragma unroll
        for (int half = 0; half < 2; ++half) {
            f32x4 acc[4][3];
#pragma unroll
            for (int mt = 0; mt < 4; ++mt)
#pragma unroll
                for (int tt = 0; tt < 3; ++tt) acc[mt][tt] = f32x4{0.f, 0.f, 0.f, 0.f};
#pragma unroll
            for (int ks = 0; ks < 8; ++ks) {
                s16x8 a[4];
#pragma unroll
                for (int mt = 0; mt < 4; ++mt) {
                    const float* xp = xbase[mt] + ks * 32 + g * 8;
                    float4 lo = *(const float4*)xp;
                    float4 hi = *(const float4*)(xp + 4);
                    u32x4 t4;
                    t4[0] = pk2(lo.x, lo.y); t4[1] = pk2(lo.z, lo.w);
                    t4[2] = pk2(hi.x, hi.y); t4[3] = pk2(hi.z, hi.w);
                    a[mt] = __builtin_bit_cast(s16x8, t4);
                }
                if (c > 0) a[3] = zfrag;   // token rows 49..63 are zero-padded
#pragma unroll
                for (int tt = 0; tt < 3; ++tt) {
                    int t = half * 3 + tt;
                    s16x8 bb = *(const s16x8*)&qkvwC[(((hh * 6 + t) * 8 + ks) * 64 + lane) * 8];
#pragma unroll
                    for (int mt = 0; mt < 4; ++mt)
                        acc[mt][tt] = __builtin_amdgcn_mfma_f32_16x16x32_bf16(a[mt], bb, acc[mt][tt], 0, 0, 0);
                }
            }
            // distribute to wave-private Q / K / V^T
#pragma unroll
            for (int tt = 0; tt < 3; ++tt) {
                int t = half * 3 + tt;
                float bv = qkv_b[(t >> 1) * 256 + hh * 32 + (t & 1) * 16 + c];
                if (t < 4) {
                    int base = (t < 2) ? PW : PW + 2000;
                    float sc = (t < 2) ? QK_SCALE : 1.0f;
#pragma unroll
                    for (int mt = 0; mt < 4; ++mt)
#pragma unroll
                        for (int j = 0; j < 4; ++j) {
                            int row = mt * 16 + g * 4 + j;
                            if (row < 50)
                                sm[base + row * 40 + (t & 1) * 16 + c] = f2bf((acc[mt][tt][j] + bv) * sc);
                        }
                } else {
#pragma unroll
                    for (int mt = 0; mt < 4; ++mt) {
                        u32 p0 = pk2(acc[mt][tt][0] + bv, acc[mt][tt][1] + bv);
                        u32 p1 = pk2(acc[mt][tt][2] + bv, acc[mt][tt][3] + bv);
                        int addr = PW + 4000 + ((t & 1) * 16 + c) * 72 + mt * 16 + g * 4;
                        *(u32*)&sm[addr] = p0;
                        *(u32*)&sm[addr + 2] = p1;
                    }
                }
            }
        }

        // ---- QK^T + bias + mask, wave-local softmax ----
        s16x8 aq[4], bk[4];
#pragma unroll
        for (int mt = 0; mt < 4; ++mt) {
            int row = mt * 16 + c; row = row > 49 ? 49 : row;
            aq[mt] = *(const s16x8*)&sm[PW + row * 40 + g * 8];
        }
#pragma unroll
        for (int nt = 0; nt < 4; ++nt) {
            int row = nt * 16 + c; row = row > 49 ? 49 : row;
            bk[nt] = *(const s16x8*)&sm[PW + 2000 + row * 40 + g * 8];
        }
        float lv[4][4][4], mx[4][4];
#pragma unroll
        for (int mt = 0; mt < 4; ++mt)
#pragma unroll
            for (int j = 0; j < 4; ++j) mx[mt][j] = -1e30f;
#pragma unroll
        for (int mt = 0; mt < 4; ++mt)
#pragma unroll
            for (int nt = 0; nt < 4; ++nt) {
                f32x4 z = {0.f, 0.f, 0.f, 0.f};
                f32x4 s4 = __builtin_amdgcn_mfma_f32_16x16x32_bf16(aq[mt], bk[nt], z, 0, 0, 0);
                f32x4 bb = *(const f32x4*)&biasC[((hh * 16 + mt * 4 + nt) * 64 + lane) * 4];
                f32x4 mm = *(const f32x4*)&maskC[((wi * 16 + mt * 4 + nt) * 64 + lane) * 4];
#pragma unroll
                for (int j = 0; j < 4; ++j) {
                    float v = s4[j] + bb[j] + mm[j];
                    lv[mt][nt][j] = v;
                    mx[mt][j] = fmaxf(mx[mt][j], v);
                }
            }
#pragma unroll
        for (int mt = 0; mt < 4; ++mt)
#pragma unroll
            for (int j = 0; j < 4; ++j) {
                float m = mx[mt][j];
                m = fmaxf(m, __shfl_xor(m, 1));
                m = fmaxf(m, __shfl_xor(m, 2));
                m = fmaxf(m, __shfl_xor(m, 4));
                m = fmaxf(m, __shfl_xor(m, 8));
                mx[mt][j] = m;
            }
        float sums[4][4];
#pragma unroll
        for (int mt = 0; mt < 4; ++mt)
#pragma unroll
            for (int j = 0; j < 4; ++j) sums[mt][j] = 0.f;
#pragma unroll
        for (int mt = 0; mt < 4; ++mt)
#pragma unroll
            for (int nt = 0; nt < 4; ++nt)
#pragma unroll
                for (int j = 0; j < 4; ++j) {
                    float e = __expf(lv[mt][nt][j] - mx[mt][j]);
                    lv[mt][nt][j] = e;
                    sums[mt][j] += e;
                }
#pragma unroll
        for (int mt = 0; mt < 4; ++mt)
#pragma unroll
            for (int j = 0; j < 4; ++j) {
                float s = sums[mt][j];
                s += __shfl_xor(s, 1);
                s += __shfl_xor(s, 2);
                s += __shfl_xor(s, 4);
                s += __shfl_xor(s, 8);
                sums[mt][j] = 1.0f / s;     // normalization deferred to PV output
            }
        // write unnormalized P (overlaps dead Q+K)
#pragma unroll
        for (int mt = 0; mt < 4; ++mt)
#pragma unroll
            for (int nt = 0; nt < 4; ++nt)
#pragma unroll
                for (int j = 0; j < 4; ++j) {
                    int row = mt * 16 + g * 4 + j;
                    if (row < 50) sm[PW + row * 72 + nt * 16 + c] = f2bf(lv[mt][nt][j]);
                }

        // ---- PV ----
        f32x4 o[4][2];
#pragma unroll
        for (int mt = 0; mt < 4; ++mt)
#pragma unroll
            for (int n2 = 0; n2 < 2; ++n2) o[mt][n2] = f32x4{0.f, 0.f, 0.f, 0.f};
#pragma unroll
        for (int ks2 = 0; ks2 < 2; ++ks2) {
            s16x8 ap[4], bv2[2];
#pragma unroll
            for (int mt = 0; mt < 4; ++mt) {
                int row = mt * 16 + c; row = row > 49 ? 49 : row;
                ap[mt] = *(const s16x8*)&sm[PW + row * 72 + ks2 * 32 + g * 8];
            }
#pragma unroll
            for (int n2 = 0; n2 < 2; ++n2)
                bv2[n2] = *(const s16x8*)&sm[PW + 4000 + (n2 * 16 + c) * 72 + ks2 * 32 + g * 8];
#pragma unroll
            for (int mt = 0; mt < 4; ++mt)
#pragma unroll
                for (int n2 = 0; n2 < 2; ++n2)
                    o[mt][n2] = __builtin_amdgcn_mfma_f32_16x16x32_bf16(ap[mt], bv2[n2], o[mt][n2], 0, 0, 0);
        }
        // normalize + pack to bf16 pairs
#pragma unroll
        for (int mt = 0; mt < 4; ++mt)
#pragma unroll
            for (int n2 = 0; n2 < 2; ++n2) {
                opk[hl][mt][n2][0] = pk2(o[mt][n2][0] * sums[mt][0], o[mt][n2][1] * sums[mt][1]);
                opk[hl][mt][n2][1] = pk2(o[mt][n2][2] * sums[mt][2], o[mt][n2][3] * sums[mt][3]);
            }
    }

    __syncthreads();   // all waves done with private scratch
    // stage head outputs into OUTS (overlaps wave scratch)
#pragma unroll
    for (int hl = 0; hl < 2; ++hl)
#pragma unroll
        for (int mt = 0; mt < 4; ++mt)
#pragma unroll
            for (int n2 = 0; n2 < 2; ++n2)
#pragma unroll
                for (int jj = 0; jj < 2; ++jj) {
                    u32 w = opk[hl][mt][n2][jj];
                    int row = mt * 16 + g * 4 + jj * 2;
                    int colb = (wv * 2 + hl) * 32 + n2 * 16 + c;
                    if (row < 49)     sm[row * 264 + colb] = (u16)(w & 0xffffu);
                    if (row + 1 < 49) sm[(row + 1) * 264 + colb] = (u16)(w >> 16);
                }
    __syncthreads();

    // ---- output projection: wave wv covers cols [wv*64, wv*64+64) ----
    f32x4 pacc[4][4];
#pragma unroll
    for (int mt = 0; mt < 4; ++mt)
#pragma unroll
        for (int n = 0; n < 4; ++n) pacc[mt][n] = f32x4{0.f, 0.f, 0.f, 0.f};
#pragma unroll
    for (int ks = 0; ks < 8; ++ks) {
        s16x8 ao[4];
#pragma unroll
        for (int mt = 0; mt < 4; ++mt) {
            int row = mt * 16 + c; row = row > 48 ? 48 : row;
            ao[mt] = *(const s16x8*)&sm[row * 264 + ks * 32 + g * 8];
        }
#pragma unroll
        for (int n = 0; n < 4; ++n) {
            s16x8 bp = *(const s16x8*)&projwC[(((wv * 4 + n) * 8 + ks) * 64 + lane) * 8];
#pragma unroll
            for (int mt = 0; mt < 4; ++mt)
                pacc[mt][n] = __builtin_amdgcn_mfma_f32_16x16x32_bf16(ao[mt], bp, pacc[mt][n], 0, 0, 0);
        }
    }
    float* ob = out + (size_t)b * 12544;
#pragma unroll
    for (int n = 0; n < 4; ++n) {
        int col = (wv * 4 + n) * 16 + c;
        float pb = proj_b[col];
#pragma unroll
        for (int mt = 0; mt < 4; ++mt)
#pragma unroll
            for (int j = 0; j < 4; ++j) {
                int row = mt * 16 + g * 4 + j;
                if (row < 49) ob[row * 256 + col] = pacc[mt][n][j] + pb;
            }
    }
}

extern "C" void kernel_launch(void* const* d_in, const int* in_sizes, int n_in,
                              void* d_out, int out_size, void* d_ws, size_t ws_size,
                              hipStream_t stream) {
    const float* x          = (const float*)d_in[0];
    const float* mask       = (const float*)d_in[1];
    const float* qkv_w      = (const float*)d_in[2];
    const float* qkv_b      = (const float*)d_in[3];
    const float* bias_table = (const float*)d_in[4];
    const float* proj_w     = (const float*)d_in[5];
    const float* proj_b     = (const float*)d_in[6];
    const int*   rel_index  = (const int*)d_in[7];

    u16*   qkvwC  = (u16*)d_ws;
    u16*   projwC = (u16*)((char*)d_ws + WS_PROJW);
    float* biasC  = (float*)((char*)d_ws + WS_BIASC);
    float* maskC  = (float*)((char*)d_ws + WS_MASKC);

    prep<<<1024, 256, 0, stream>>>(qkv_w, proj_w, bias_table, rel_index, mask,
                                   qkvwC, projwC, biasC, maskC);
    swin_attn<<<2048, 256, 0, stream>>>(x, qkv_b, proj_b, qkvwC, projwC, biasC, maskC,
                                        (float*)d_out);
}

// Round 6
// 198.591 us; speedup vs baseline: 1.6407x; 1.6407x over previous
//
#include <hip/hip_runtime.h>

typedef float f32x4 __attribute__((ext_vector_type(4)));
typedef short s16x8 __attribute__((ext_vector_type(8)));
typedef unsigned int u32x4 __attribute__((ext_vector_type(4)));
typedef unsigned short u16;
typedef unsigned int u32;

#define QK_SCALE 0.17677669529663687f  // 32^-0.5

__device__ __forceinline__ u16 f2bf(float f) {
    unsigned u = __builtin_bit_cast(unsigned, f);
    u = (u + 0x7fffu + ((u >> 16) & 1u)) >> 16;
    return (u16)u;
}
__device__ __forceinline__ u32 pk2(float lo, float hi) {
    return (u32)f2bf(lo) | ((u32)f2bf(hi) << 16);
}

// C-frag(pair) -> operand-frag conversion (see lemma in analysis):
// dst lane (c,g) elem e needs M[t=c][u=8g+e]; src lane (c, 2(g&1)+(e>>2)),
// utile=g>>1, j=e&3.  r0/r1 = packed (j0,j1)/(j2,j3) words per utile.
__device__ __forceinline__ s16x8 frag4(u32 r0u0, u32 r1u0, u32 r0u1, u32 r1u1,
                                       int aA, int aB, bool lo) {
    u32x4 w;
    u32 a, bq;
    a  = (u32)__builtin_amdgcn_ds_bpermute(aA, (int)r0u0);
    bq = (u32)__builtin_amdgcn_ds_bpermute(aA, (int)r0u1);
    w[0] = lo ? a : bq;
    a  = (u32)__builtin_amdgcn_ds_bpermute(aA, (int)r1u0);
    bq = (u32)__builtin_amdgcn_ds_bpermute(aA, (int)r1u1);
    w[1] = lo ? a : bq;
    a  = (u32)__builtin_amdgcn_ds_bpermute(aB, (int)r0u0);
    bq = (u32)__builtin_amdgcn_ds_bpermute(aB, (int)r0u1);
    w[2] = lo ? a : bq;
    a  = (u32)__builtin_amdgcn_ds_bpermute(aB, (int)r1u0);
    bq = (u32)__builtin_amdgcn_ds_bpermute(aB, (int)r1u1);
    w[3] = lo ? a : bq;
    return __builtin_bit_cast(s16x8, w);
}

// ---- workspace byte offsets ----
// wqkvC2: 196608 bf16 [h8][t3][dt2][ks8][lane64][e8]  (A-frags of W, lane&15 = d-row)
// projwC:  65536 bf16 [nt16][ks8][lane64][e8]
// biasC2:  32768 f32  [h8][ntQ4][mtK4][lane64][j4]  (k'>=49 -> -1e30)
// maskC2: 262144 f32  [wi64][ntQ4][mtK4][lane64][j4]
// vbias :  12288 f32  [h8][t3][dt2][lane64][j4]
#define WS_PROJW 393216
#define WS_BIASC 524288
#define WS_MASKC 655360
#define WS_VBIAS 1703936

__global__ void prep(const float* __restrict__ qkv_w, const float* __restrict__ proj_w,
                     const float* __restrict__ bias_table, const int* __restrict__ rel_index,
                     const float* __restrict__ mask, const float* __restrict__ qkv_b,
                     u16* __restrict__ wqkvC2, u16* __restrict__ projwC,
                     float* __restrict__ biasC2, float* __restrict__ maskC2,
                     float* __restrict__ vbias) {
    int i = blockIdx.x * 256 + threadIdx.x;
    if (i < 196608) {                       // qkv weights as A-frags of W·X^T
        int e = i & 7, lane = (i >> 3) & 63, ks = (i >> 9) & 7, dt = (i >> 12) & 1;
        int i2 = i >> 13, t = i2 % 3, h = i2 / 3;
        int c = lane & 15, g = lane >> 4;
        wqkvC2[i] = f2bf(qkv_w[(t * 256 + h * 32 + dt * 16 + c) * 256 + ks * 32 + g * 8 + e]);
    }
    if (i < 65536) {                        // proj weights -> fragment order (unchanged)
        int e = i & 7, lane = (i >> 3) & 63, ks = (i >> 9) & 7, nt = (i >> 12) & 15;
        int c = lane & 15, g = lane >> 4;
        projwC[i] = f2bf(proj_w[(nt * 16 + c) * 256 + ks * 32 + g * 8 + e]);
    }
    if (i < 32768) {                        // rel-pos bias in St C-frag order
        int j = i & 3, lane = (i >> 2) & 63, mtK = (i >> 8) & 3, ntQ = (i >> 10) & 3, h = i >> 12;
        int c = lane & 15, g = lane >> 4;
        int q = ntQ * 16 + c, k = mtK * 16 + g * 4 + j;
        float v;
        if (k < 49) v = (q < 49) ? bias_table[rel_index[q * 49 + k] * 8 + h] : 0.f;
        else        v = -1e30f;
        biasC2[i] = v;
    }
    if (i < 262144) {                       // shift mask in St C-frag order
        int j = i & 3, lane = (i >> 2) & 63, mtK = (i >> 8) & 3, ntQ = (i >> 10) & 3, wi = i >> 12;
        int c = lane & 15, g = lane >> 4;
        int q = ntQ * 16 + c, k = mtK * 16 + g * 4 + j;
        maskC2[i] = (q < 49 && k < 49) ? mask[wi * 2401 + q * 49 + k] : 0.f;
    }
    if (i < 12288) {                        // qkv bias in C-frag row order
        int j = i & 3, lane = (i >> 2) & 63, dt = (i >> 8) & 1;
        int i2 = i >> 9, t = i2 % 3, h = i2 / 3;
        int g = lane >> 4;
        vbias[i] = qkv_b[t * 256 + h * 32 + dt * 16 + g * 4 + j];
    }
}

// ---- LDS (u16 offsets), total 22152 u16 = 44,304 B -> 3 blocks/CU ----
// XS  : [0, 12936)  49 rows x 264  (x window, bf16)
// VT  : 12936 + wv*2304, [d32][tok72-pad] per wave
// OUTS: [0, 12936)  overlaps XS after barrier
__global__ __launch_bounds__(256, 3)
void swin_attn(const float* __restrict__ x,
               const float* __restrict__ proj_b,
               const u16* __restrict__ wqkvC2,
               const u16* __restrict__ projwC,
               const float* __restrict__ biasC2,
               const float* __restrict__ maskC2,
               const float* __restrict__ vbias,
               float* __restrict__ out) {
    __shared__ __align__(16) u16 sm[22152];
    const int b = blockIdx.x, tid = threadIdx.x;
    const int wv = tid >> 6, lane = tid & 63, g = lane >> 4, c = lane & 15;
    const int wi = b & 63;
    const int VTb = 12936 + wv * 2304;
    const float* xw = x + (size_t)b * 12544;

    // stage x window (bf16), rows 0..48
    for (int i = tid; i < 49 * 64; i += 256) {
        int row = i >> 6, q4 = i & 63;
        float4 v = ((const float4*)xw)[i];
        ushort4 s;
        s.x = f2bf(v.x); s.y = f2bf(v.y); s.z = f2bf(v.z); s.w = f2bf(v.w);
        *(ushort4*)&sm[row * 264 + q4 * 4] = s;
    }
    __syncthreads();

    const int addrA = ((lane & 15) + ((lane & 16) << 1)) << 2;  // src lane c+32*(g&1)
    const int addrB = addrA + 64;                               // +16 lanes
    const bool lo = lane < 32;                                  // utile = g>>1
    const s16x8 zfrag = {0, 0, 0, 0, 0, 0, 0, 0};

    u32 opk[2][4][2][2];

#pragma unroll
    for (int hl = 0; hl < 2; ++hl) {
        const int h = wv * 2 + hl;

        // ---- QKV as W·X^T: acc[t][dt][tt], A = W-frag, B = X-frag from XS ----
        f32x4 acc[3][2][4];
#pragma unroll
        for (int t = 0; t < 3; ++t)
#pragma unroll
            for (int dt = 0; dt < 2; ++dt)
#pragma unroll
                for (int tt = 0; tt < 4; ++tt) acc[t][dt][tt] = f32x4{0.f, 0.f, 0.f, 0.f};
#pragma unroll
        for (int ks = 0; ks < 8; ++ks) {
            s16x8 Xf[4];
#pragma unroll
            for (int tt = 0; tt < 4; ++tt)
                Xf[tt] = *(const s16x8*)&sm[(tt * 16 + c) * 264 + ks * 32 + g * 8];
            if (c > 0) Xf[3] = zfrag;      // tokens 49..63 zero
#pragma unroll
            for (int t = 0; t < 3; ++t)
#pragma unroll
                for (int dt = 0; dt < 2; ++dt) {
                    s16x8 Wf = *(const s16x8*)&wqkvC2[(((((h * 3 + t) * 2 + dt) * 8 + ks) * 64) + lane) * 8];
#pragma unroll
                    for (int tt = 0; tt < 4; ++tt)
                        acc[t][dt][tt] = __builtin_amdgcn_mfma_f32_16x16x32_bf16(Wf, Xf[tt], acc[t][dt][tt], 0, 0, 0);
                }
        }

        // ---- bias, pack Qt/Kt to regs; Vt -> VT LDS ----
        u32 qp[4][2][2], kp[4][2][2];
#pragma unroll
        for (int t = 0; t < 3; ++t)
#pragma unroll
            for (int dt = 0; dt < 2; ++dt) {
                f32x4 bv = *(const f32x4*)&vbias[(((h * 3 + t) * 2 + dt) * 64 + lane) * 4];
#pragma unroll
                for (int tt = 0; tt < 4; ++tt) {
                    float v0 = acc[t][dt][tt][0] + bv[0];
                    float v1 = acc[t][dt][tt][1] + bv[1];
                    float v2 = acc[t][dt][tt][2] + bv[2];
                    float v3 = acc[t][dt][tt][3] + bv[3];
                    if (t == 0) {
                        qp[tt][dt][0] = pk2(v0 * QK_SCALE, v1 * QK_SCALE);
                        qp[tt][dt][1] = pk2(v2 * QK_SCALE, v3 * QK_SCALE);
                    } else if (t == 1) {
                        kp[tt][dt][0] = pk2(v0, v1);
                        kp[tt][dt][1] = pk2(v2, v3);
                    } else {
                        sm[VTb + (dt * 16 + g * 4 + 0) * 72 + tt * 16 + c] = f2bf(v0);
                        sm[VTb + (dt * 16 + g * 4 + 1) * 72 + tt * 16 + c] = f2bf(v1);
                        sm[VTb + (dt * 16 + g * 4 + 2) * 72 + tt * 16 + c] = f2bf(v2);
                        sm[VTb + (dt * 16 + g * 4 + 3) * 72 + tt * 16 + c] = f2bf(v3);
                    }
                }
            }

        // ---- operand frags for St = K·Q^T (both lane&15 = token) ----
        s16x8 Qf[4], Kf[4];
#pragma unroll
        for (int nt = 0; nt < 4; ++nt)
            Qf[nt] = frag4(qp[nt][0][0], qp[nt][0][1], qp[nt][1][0], qp[nt][1][1], addrA, addrB, lo);
#pragma unroll
        for (int mt = 0; mt < 4; ++mt)
            Kf[mt] = frag4(kp[mt][0][0], kp[mt][0][1], kp[mt][1][0], kp[mt][1][1], addrA, addrB, lo);

        // ---- St (16 MFMA) + bias + mask, softmax (q = c, k' = mtK*16+g*4+j) ----
        f32x4 lv[4][4];
#pragma unroll
        for (int mtK = 0; mtK < 4; ++mtK)
#pragma unroll
            for (int ntQ = 0; ntQ < 4; ++ntQ) {
                f32x4 z = {0.f, 0.f, 0.f, 0.f};
                lv[mtK][ntQ] = __builtin_amdgcn_mfma_f32_16x16x32_bf16(Kf[mtK], Qf[ntQ], z, 0, 0, 0);
            }
        float mx[4] = {-1e30f, -1e30f, -1e30f, -1e30f};
#pragma unroll
        for (int ntQ = 0; ntQ < 4; ++ntQ)
#pragma unroll
            for (int mtK = 0; mtK < 4; ++mtK) {
                f32x4 bb = *(const f32x4*)&biasC2[((h * 16 + ntQ * 4 + mtK) * 64 + lane) * 4];
                f32x4 mm = *(const f32x4*)&maskC2[((wi * 16 + ntQ * 4 + mtK) * 64 + lane) * 4];
#pragma unroll
                for (int j = 0; j < 4; ++j) {
                    float v = lv[mtK][ntQ][j] + bb[j] + mm[j];
                    lv[mtK][ntQ][j] = v;
                    mx[ntQ] = fmaxf(mx[ntQ], v);
                }
            }
#pragma unroll
        for (int ntQ = 0; ntQ < 4; ++ntQ) {
            float m = mx[ntQ];
            m = fmaxf(m, __shfl_xor(m, 16));
            m = fmaxf(m, __shfl_xor(m, 32));
            mx[ntQ] = m;
        }
        float sums[4] = {0.f, 0.f, 0.f, 0.f};
#pragma unroll
        for (int ntQ = 0; ntQ < 4; ++ntQ)
#pragma unroll
            for (int mtK = 0; mtK < 4; ++mtK)
#pragma unroll
                for (int j = 0; j < 4; ++j) {
                    float e = __expf(lv[mtK][ntQ][j] - mx[ntQ]);
                    lv[mtK][ntQ][j] = e;
                    sums[ntQ] += e;
                }
#pragma unroll
        for (int ntQ = 0; ntQ < 4; ++ntQ) {
            float s = sums[ntQ];
            s += __shfl_xor(s, 16);
            s += __shfl_xor(s, 32);
            sums[ntQ] = 1.0f / s;
        }
        // normalized P packed (q = c, so inv-sum is lane-local)
        u32 pp[4][4][2];
#pragma unroll
        for (int mtK = 0; mtK < 4; ++mtK)
#pragma unroll
            for (int ntQ = 0; ntQ < 4; ++ntQ) {
                float is = sums[ntQ];
                pp[mtK][ntQ][0] = pk2(lv[mtK][ntQ][0] * is, lv[mtK][ntQ][1] * is);
                pp[mtK][ntQ][1] = pk2(lv[mtK][ntQ][2] * is, lv[mtK][ntQ][3] * is);
            }

        // ---- PV: A = P-frag (bpermute), B = VT from LDS ----
        f32x4 o[4][2];
#pragma unroll
        for (int mtQ = 0; mtQ < 4; ++mtQ)
#pragma unroll
            for (int ndt = 0; ndt < 2; ++ndt) o[mtQ][ndt] = f32x4{0.f, 0.f, 0.f, 0.f};
#pragma unroll
        for (int mtQ = 0; mtQ < 4; ++mtQ)
#pragma unroll
            for (int ks2 = 0; ks2 < 2; ++ks2) {
                s16x8 Pf = frag4(pp[2 * ks2][mtQ][0], pp[2 * ks2][mtQ][1],
                                 pp[2 * ks2 + 1][mtQ][0], pp[2 * ks2 + 1][mtQ][1], addrA, addrB, lo);
#pragma unroll
                for (int ndt = 0; ndt < 2; ++ndt) {
                    s16x8 Vf = *(const s16x8*)&sm[VTb + (ndt * 16 + c) * 72 + ks2 * 32 + g * 8];
                    o[mtQ][ndt] = __builtin_amdgcn_mfma_f32_16x16x32_bf16(Pf, Vf, o[mtQ][ndt], 0, 0, 0);
                }
            }
#pragma unroll
        for (int mtQ = 0; mtQ < 4; ++mtQ)
#pragma unroll
            for (int ndt = 0; ndt < 2; ++ndt) {
                opk[hl][mtQ][ndt][0] = pk2(o[mtQ][ndt][0], o[mtQ][ndt][1]);
                opk[hl][mtQ][ndt][1] = pk2(o[mtQ][ndt][2], o[mtQ][ndt][3]);
            }
    }

    __syncthreads();   // all waves done with XS reads
    // stage head outputs into OUTS (overlaps XS)
#pragma unroll
    for (int hl = 0; hl < 2; ++hl)
#pragma unroll
        for (int mt = 0; mt < 4; ++mt)
#pragma unroll
            for (int n2 = 0; n2 < 2; ++n2)
#pragma unroll
                for (int jj = 0; jj < 2; ++jj) {
                    u32 w = opk[hl][mt][n2][jj];
                    int row = mt * 16 + g * 4 + jj * 2;
                    int colb = (wv * 2 + hl) * 32 + n2 * 16 + c;
                    if (row < 49)     sm[row * 264 + colb] = (u16)(w & 0xffffu);
                    if (row + 1 < 49) sm[(row + 1) * 264 + colb] = (u16)(w >> 16);
                }
    __syncthreads();

    // ---- output projection: wave wv covers cols [wv*64, wv*64+64) ----
    f32x4 pacc[4][4];
#pragma unroll
    for (int mt = 0; mt < 4; ++mt)
#pragma unroll
        for (int n = 0; n < 4; ++n) pacc[mt][n] = f32x4{0.f, 0.f, 0.f, 0.f};
#pragma unroll
    for (int ks = 0; ks < 8; ++ks) {
        s16x8 ao[4];
#pragma unroll
        for (int mt = 0; mt < 4; ++mt) {
            int row = mt * 16 + c; row = row > 48 ? 48 : row;
            ao[mt] = *(const s16x8*)&sm[row * 264 + ks * 32 + g * 8];
        }
#pragma unroll
        for (int n = 0; n < 4; ++n) {
            s16x8 bp = *(const s16x8*)&projwC[(((wv * 4 + n) * 8 + ks) * 64 + lane) * 8];
#pragma unroll
            for (int mt = 0; mt < 4; ++mt)
                pacc[mt][n] = __builtin_amdgcn_mfma_f32_16x16x32_bf16(ao[mt], bp, pacc[mt][n], 0, 0, 0);
        }
    }
    float* ob = out + (size_t)b * 12544;
#pragma unroll
    for (int n = 0; n < 4; ++n) {
        int col = (wv * 4 + n) * 16 + c;
        float pb = proj_b[col];
#pragma unroll
        for (int mt = 0; mt < 4; ++mt)
#pragma unroll
            for (int j = 0; j < 4; ++j) {
                int row = mt * 16 + g * 4 + j;
                if (row < 49) ob[row * 256 + col] = pacc[mt][n][j] + pb;
            }
    }
}

extern "C" void kernel_launch(void* const* d_in, const int* in_sizes, int n_in,
                              void* d_out, int out_size, void* d_ws, size_t ws_size,
                              hipStream_t stream) {
    const float* x          = (const float*)d_in[0];
    const float* mask       = (const float*)d_in[1];
    const float* qkv_w      = (const float*)d_in[2];
    const float* qkv_b      = (const float*)d_in[3];
    const float* bias_table = (const float*)d_in[4];
    const float* proj_w     = (const float*)d_in[5];
    const float* proj_b     = (const float*)d_in[6];
    const int*   rel_index  = (const int*)d_in[7];

    u16*   wqkvC2 = (u16*)d_ws;
    u16*   projwC = (u16*)((char*)d_ws + WS_PROJW);
    float* biasC2 = (float*)((char*)d_ws + WS_BIASC);
    float* maskC2 = (float*)((char*)d_ws + WS_MASKC);
    float* vbias  = (float*)((char*)d_ws + WS_VBIAS);

    prep<<<1024, 256, 0, stream>>>(qkv_w, proj_w, bias_table, rel_index, mask, qkv_b,
                                   wqkvC2, projwC, biasC2, maskC2, vbias);
    swin_attn<<<2048, 256, 0, stream>>>(x, proj_b, wqkvC2, projwC, biasC2, maskC2, vbias,
                                        (float*)d_out);
}